// Round 9
// baseline (625.943 us; speedup 1.0000x reference)
//
#include <hip/hip_runtime.h>
#include <hip/hip_fp16.h>
#include <math.h>

typedef unsigned long long u64;
typedef unsigned int u32;

__device__ __forceinline__ float lrelu(float v) { return v > 0.f ? v : 0.2f * v; }
__device__ __forceinline__ u32 fkey(float x) {
    u32 b = __float_as_uint(x);
    return (b & 0x80000000u) ? ~b : (b | 0x80000000u);
}
__device__ __forceinline__ float finv(u32 k) {
    return __uint_as_float((k & 0x80000000u) ? (k & 0x7fffffffu) : ~k);
}

union H2U { __half2 h; u32 u; };

// ---------- CSR build (dst-CSR, packed u32: w15<<17 | src17) ----------
// k_hist / k_fill / k_gatsm are XCD-partitioned: blockIdx%8 -> XCD (round-robin
// dispatch); exclusive dst-ranges (hist/fill) or private wpk copies (gatsm) keep
// scattered-RMW lines resident in ONE XCD L2 -> written back once.

__global__ __launch_bounds__(256) void k_hist(const int* __restrict__ dst,
                                              int* __restrict__ cnt, int E, int N) {
    int p = blockIdx.x & 7;
    int lo = (int)((long long)p * N / 8);
    int hi = (int)((long long)(p + 1) * N / 8);
    int bi = blockIdx.x >> 3;
    int nb = gridDim.x >> 3;
    for (int e = bi * 256 + threadIdx.x; e < E; e += nb * 256) {
        int d = dst[e];
        if (d >= lo && d < hi) atomicAdd(&cnt[d], 1);
    }
}

__global__ __launch_bounds__(256) void k_scan1(const int* __restrict__ cnt,
                                               int* __restrict__ off,
                                               int* __restrict__ partials, int N) {
    __shared__ int sh[256];
    int tid = threadIdx.x;
    int base = blockIdx.x * 1024 + tid * 4;
    int v[4]; int tsum = 0;
#pragma unroll
    for (int i = 0; i < 4; i++) {
        int n = base + i;
        int c = (n < N) ? cnt[n] + 1 : 0;
        v[i] = tsum; tsum += c;
    }
    sh[tid] = tsum; __syncthreads();
    int mine = tsum;
    for (int o = 1; o < 256; o <<= 1) {
        int t = (tid >= o) ? sh[tid - o] : 0;
        __syncthreads();
        sh[tid] += t;
        __syncthreads();
    }
    int excl = sh[tid] - mine;
#pragma unroll
    for (int i = 0; i < 4; i++) {
        int n = base + i;
        if (n < N) off[n] = excl + v[i];
    }
    if (tid == 255) partials[blockIdx.x] = sh[255];
}

__global__ void k_scan2(int* __restrict__ partials, int nb) {
    __shared__ int sh[256];
    int tid = threadIdx.x;
    int v = (tid < nb) ? partials[tid] : 0;
    sh[tid] = v; __syncthreads();
    for (int o = 1; o < 256; o <<= 1) {
        int t = (tid >= o) ? sh[tid - o] : 0;
        __syncthreads();
        sh[tid] += t;
        __syncthreads();
    }
    if (tid < nb) partials[tid] = sh[tid] - v;
}

__global__ void k_scan3(int* __restrict__ off, int* __restrict__ cursor,
                        const int* __restrict__ partials, int N, int Et) {
    int base = blockIdx.x * 1024 + threadIdx.x * 4;
    int add = partials[blockIdx.x];
#pragma unroll
    for (int i = 0; i < 4; i++) {
        int n = base + i;
        if (n < N) { int o = off[n] + add; off[n] = o; cursor[n] = o; }
    }
    if (blockIdx.x == 0 && threadIdx.x == 0) { off[N] = Et; cursor[N] = Et; }
}

__global__ __launch_bounds__(256) void k_fill(const int* __restrict__ src,
                                              const int* __restrict__ dst,
                                              const float* __restrict__ ew,
                                              int* __restrict__ cursor,
                                              u32* __restrict__ epk,
                                              int E, int Et, int N) {
    int p = blockIdx.x & 7;
    int lo = (int)((long long)p * N / 8);
    int hi = (int)((long long)(p + 1) * N / 8);
    int bi = blockIdx.x >> 3;
    int nb = gridDim.x >> 3;
    for (int e = bi * 256 + threadIdx.x; e < Et; e += nb * 256) {
        int d = (e < E) ? dst[e] : e - E;
        if (d < lo || d >= hi) continue;
        int s; u32 q;
        if (e < E) {
            s = src[e];
            q = min(__float2uint_rn(ew[e] * 32767.f), 32767u);
        } else { s = d; q = 32767u; }
        int pos = atomicAdd(&cursor[d], 1);
        epk[pos] = (q << 17) | (u32)s;
    }
}

__global__ void k_degdis(const int* __restrict__ off, const u32* __restrict__ epk,
                         float* __restrict__ dis, int N) {
    int n = blockIdx.x * 256 + threadIdx.x;
    if (n >= N) return;
    int b = off[n], e2 = off[n + 1];
    float s = 0.f;
    for (int i = b; i < e2; i++) s += (float)(epk[i] >> 17);
    dis[n] = rsqrtf(s * (1.f / 32767.f));
}

// ---------- dense kernels ----------

// xwh[n] = f16( dis[n] * (X @ W1)[n] )
__global__ __launch_bounds__(256) void k_gemm1(const float* __restrict__ X,
                                               const float* __restrict__ W1,
                                               const float* __restrict__ dis,
                                               __half* __restrict__ xwh, int N) {
    __shared__ __align__(16) float Ws[128 * 64];
    __shared__ __align__(16) float Xs[32][129];
    int tid = threadIdx.x;
    int m0 = blockIdx.x * 32;
    const float4* W4 = (const float4*)W1;
    float4* Ws4 = (float4*)Ws;
#pragma unroll
    for (int i = 0; i < 8; i++) Ws4[tid + i * 256] = W4[tid + i * 256];
#pragma unroll
    for (int i = 0; i < 4; i++) {
        int idx = tid + i * 256;
        int r = idx >> 5;
        int c = idx & 31;
        float4 v = ((const float4*)(X + (size_t)(m0 + r) * 128))[c];
        Xs[r][c * 4 + 0] = v.x; Xs[r][c * 4 + 1] = v.y;
        Xs[r][c * 4 + 2] = v.z; Xs[r][c * 4 + 3] = v.w;
    }
    __syncthreads();
    int r = tid & 31;
    int c0 = (tid >> 5) * 8;
    float acc[8] = {0, 0, 0, 0, 0, 0, 0, 0};
#pragma unroll 4
    for (int k = 0; k < 128; k++) {
        float xv = Xs[r][k];
        const float4* wr = (const float4*)&Ws[k * 64 + c0];
        float4 w0 = wr[0], w1 = wr[1];
        acc[0] += xv * w0.x; acc[1] += xv * w0.y; acc[2] += xv * w0.z; acc[3] += xv * w0.w;
        acc[4] += xv * w1.x; acc[5] += xv * w1.y; acc[6] += xv * w1.z; acc[7] += xv * w1.w;
    }
    float dn = dis[m0 + r];
    H2U p0, p1, p2, p3;
    p0.h = __floats2half2_rn(acc[0] * dn, acc[1] * dn);
    p1.h = __floats2half2_rn(acc[2] * dn, acc[3] * dn);
    p2.h = __floats2half2_rn(acc[4] * dn, acc[5] * dn);
    p3.h = __floats2half2_rn(acc[6] * dn, acc[7] * dn);
    ((uint4*)(xwh + (size_t)(m0 + r) * 64))[c0 >> 3] = make_uint4(p0.u, p1.u, p2.u, p3.u);
}

// x[n] = dis[n] * sum_{e in CSR(n)} w_e * xwh[src]   (8 edge-slots x 8 lanes)
__global__ __launch_bounds__(256) void k_gcn_agg(const int* __restrict__ off,
                                                 const u32* __restrict__ epk,
                                                 const float* __restrict__ dis,
                                                 const __half* __restrict__ xwh,
                                                 float* __restrict__ x, int N) {
    int lane = threadIdx.x & 63;
    int wv = threadIdx.x >> 6;
    int slot = lane >> 3;
    int f8 = lane & 7;
    int gw = blockIdx.x * 4 + wv;
    int stride = gridDim.x * 4;
    for (int n = gw; n < N; n += stride) {
        int b = off[n], en = off[n + 1];
        float acc[8] = {0, 0, 0, 0, 0, 0, 0, 0};
        for (int c = b; c < en; c += 64) {
            int idx = c + lane;
            int s = 0; float nw = 0.f;
            if (idx < en) {
                u32 pk = epk[idx];
                s = (int)(pk & 0x1FFFFu);
                nw = (float)(pk >> 17) * (1.f / 32767.f);
            }
            int cc = min(64, en - c);
            for (int r = 0; r * 8 < cc; r++) {
                int eo = r * 8 + slot;
                int ss = __shfl(s, eo);
                float nn = __shfl(nw, eo);
                if (eo < cc) {
                    uint4 raw = ((const uint4*)(xwh + (size_t)ss * 64))[f8];
                    __half2* hp = (__half2*)&raw;
                    float2 q0 = __half22float2(hp[0]);
                    float2 q1 = __half22float2(hp[1]);
                    float2 q2 = __half22float2(hp[2]);
                    float2 q3 = __half22float2(hp[3]);
                    acc[0] += nn * q0.x; acc[1] += nn * q0.y;
                    acc[2] += nn * q1.x; acc[3] += nn * q1.y;
                    acc[4] += nn * q2.x; acc[5] += nn * q2.y;
                    acc[6] += nn * q3.x; acc[7] += nn * q3.y;
                }
            }
        }
#pragma unroll
        for (int j = 0; j < 8; j++) {
            acc[j] += __shfl_xor(acc[j], 8);
            acc[j] += __shfl_xor(acc[j], 16);
            acc[j] += __shfl_xor(acc[j], 32);
        }
        if (lane < 8) {
            float dn = dis[n];
            ((float4*)(x + (size_t)n * 64))[f8 * 2 + 0] =
                make_float4(acc[0] * dn, acc[1] * dn, acc[2] * dn, acc[3] * dn);
            ((float4*)(x + (size_t)n * 64))[f8 * 2 + 1] =
                make_float4(acc[4] * dn, acc[5] * dn, acc[6] * dn, acc[7] * dn);
        }
    }
}

// gh = f16( relu(x + b1) @ W2 ); fused epilogue: asrc4/adst4 dots + global amax
__global__ __launch_bounds__(256) void k_gemm2(const float* __restrict__ x,
                                               const float* __restrict__ W2,
                                               const float* __restrict__ b1,
                                               const float* __restrict__ att_src,
                                               const float* __restrict__ att_dst,
                                               __half* __restrict__ gh,
                                               float* __restrict__ asrc4,
                                               float* __restrict__ adst4,
                                               u32* __restrict__ amaxk, int N) {
    __shared__ __align__(16) float Ws[64 * 192];
    __shared__ __align__(16) float Xs[32][65];
    __shared__ float b1s[64];
    __shared__ float as_s[192], ad_s[192];
    int tid = threadIdx.x;
    int m0 = blockIdx.x * 32;
    if (tid < 64) b1s[tid] = b1[tid];
    if (tid < 192) { as_s[tid] = att_src[tid]; ad_s[tid] = att_dst[tid]; }
    __syncthreads();
    const float4* W4 = (const float4*)W2;
    float4* Ws4 = (float4*)Ws;
#pragma unroll
    for (int i = 0; i < 12; i++) Ws4[tid + i * 256] = W4[tid + i * 256];
#pragma unroll
    for (int i = 0; i < 2; i++) {
        int idx = tid + i * 256;
        int r = idx >> 4;
        int c4 = idx & 15;
        float4 v = ((const float4*)(x + (size_t)(m0 + r) * 64))[c4];
        v.x = fmaxf(v.x + b1s[c4 * 4 + 0], 0.f);
        v.y = fmaxf(v.y + b1s[c4 * 4 + 1], 0.f);
        v.z = fmaxf(v.z + b1s[c4 * 4 + 2], 0.f);
        v.w = fmaxf(v.w + b1s[c4 * 4 + 3], 0.f);
        Xs[r][c4 * 4 + 0] = v.x; Xs[r][c4 * 4 + 1] = v.y;
        Xs[r][c4 * 4 + 2] = v.z; Xs[r][c4 * 4 + 3] = v.w;
    }
    __syncthreads();
    int r = tid & 31;
    int c0 = (tid >> 5) * 24;
    float acc[24];
#pragma unroll
    for (int j = 0; j < 24; j++) acc[j] = 0.f;
#pragma unroll 4
    for (int k = 0; k < 64; k++) {
        float xv = Xs[r][k];
        const float4* wr = (const float4*)&Ws[k * 192 + c0];
#pragma unroll
        for (int q = 0; q < 6; q++) {
            float4 wv = wr[q];
            acc[q * 4 + 0] += xv * wv.x;
            acc[q * 4 + 1] += xv * wv.y;
            acc[q * 4 + 2] += xv * wv.z;
            acc[q * 4 + 3] += xv * wv.w;
        }
    }
    __half* outp = gh + (size_t)(m0 + r) * 192 + c0;
#pragma unroll
    for (int t = 0; t < 3; t++) {
        H2U p0, p1, p2, p3;
        p0.h = __floats2half2_rn(acc[t * 8 + 0], acc[t * 8 + 1]);
        p1.h = __floats2half2_rn(acc[t * 8 + 2], acc[t * 8 + 3]);
        p2.h = __floats2half2_rn(acc[t * 8 + 4], acc[t * 8 + 5]);
        p3.h = __floats2half2_rn(acc[t * 8 + 6], acc[t * 8 + 7]);
        ((uint4*)outp)[t] = make_uint4(p0.u, p1.u, p2.u, p3.u);
    }

    // ---- fused attention-dot epilogue (reuses Xs as scratch) ----
    float sa0 = 0.f, sa1 = 0.f, sb0 = 0.f, sb1 = 0.f;
    int h0 = c0 >> 6;
    int split = 64 - (c0 & 63); if (split > 24) split = 24;
#pragma unroll
    for (int j = 0; j < 24; j++) {
        float va = acc[j] * as_s[c0 + j];
        float vb = acc[j] * ad_s[c0 + j];
        if (j < split) { sa0 += va; sb0 += vb; }
        else           { sa1 += va; sb1 += vb; }
    }
    __syncthreads();                 // everyone done reading Xs
    float* S = &Xs[0][0];
    for (int i = tid; i < 1536; i += 256) S[i] = 0.f;
    __syncthreads();
    int ct = tid >> 5;
    int slot = (r * 8 + ct) * 3;
    S[slot + h0] = sa0;
    S[768 + slot + h0] = sb0;
    if (split < 24) { S[slot + h0 + 1] = sa1; S[768 + slot + h0 + 1] = sb1; }
    __syncthreads();
    if (tid < 96) {
        int rr = tid / 3, h = tid - 3 * rr;
        float sA = 0.f, sB = 0.f;
#pragma unroll
        for (int c = 0; c < 8; c++) {
            sA += S[(rr * 8 + c) * 3 + h];
            sB += S[768 + (rr * 8 + c) * 3 + h];
        }
        asrc4[(size_t)(m0 + rr) * 4 + h] = sA;
        adst4[(size_t)(m0 + rr) * 4 + h] = sB;
        S[1536 + tid] = sA;
    }
    __syncthreads();
    if (tid < 3) {
        float m = -1e30f;
        for (int rr = 0; rr < 32; rr++) m = fmaxf(m, S[1536 + rr * 3 + tid]);
        atomicMax(&amaxk[tid], fkey(m));
    }
}

// 4 threads per dst node: 2 sweeps (denom with safe bound M, then attn-scatter).
// attn packed: 3 heads x 21-bit fixed point (scale 8192), scattered with one u64
// atomic into the block's XCD-private wpk copy (blockIdx%8) -> no cross-XCD churn.
__global__ __launch_bounds__(256) void k_gatsm(const int* __restrict__ off,
                                               const u32* __restrict__ epk,
                                               const float* __restrict__ asrc4,
                                               const float* __restrict__ adst4,
                                               const u32* __restrict__ amaxk,
                                               u64* __restrict__ wpk, int N) {
    int gid = blockIdx.x * 256 + threadIdx.x;
    int n = gid >> 2;
    int sub = gid & 3;
    if (n >= N) return;
    u64* wp = wpk + (size_t)(blockIdx.x & 7) * N;   // XCD-private copy
    int b = off[n], en = off[n + 1];
    float4 ad = ((const float4*)adst4)[n];
    float M0 = lrelu(finv(amaxk[0]) + ad.x);   // >= per-node max (lrelu monotone)
    float M1 = lrelu(finv(amaxk[1]) + ad.y);
    float M2 = lrelu(finv(amaxk[2]) + ad.z);
    float s0 = 0.f, s1 = 0.f, s2 = 0.f;
    for (int i = b + sub; i < en; i += 4) {
        int s = (int)(epk[i] & 0x1FFFFu);
        float4 av = ((const float4*)asrc4)[s];
        s0 += __expf(lrelu(av.x + ad.x) - M0);
        s1 += __expf(lrelu(av.y + ad.y) - M1);
        s2 += __expf(lrelu(av.z + ad.z) - M2);
    }
    // combine partial denoms across the 4-thread group (lane-quad)
    s0 += __shfl_xor(s0, 1); s0 += __shfl_xor(s0, 2);
    s1 += __shfl_xor(s1, 1); s1 += __shfl_xor(s1, 2);
    s2 += __shfl_xor(s2, 1); s2 += __shfl_xor(s2, 2);
    float i0 = 8192.f / (s0 + 1e-16f);
    float i1 = 8192.f / (s1 + 1e-16f);
    float i2 = 8192.f / (s2 + 1e-16f);
    for (int i = b + sub; i < en; i += 4) {
        int s = (int)(epk[i] & 0x1FFFFu);
        float4 av = ((const float4*)asrc4)[s];
        u32 q0 = __float2uint_rn(__expf(lrelu(av.x + ad.x) - M0) * i0);
        u32 q1 = __float2uint_rn(__expf(lrelu(av.y + ad.y) - M1) * i1);
        u32 q2 = __float2uint_rn(__expf(lrelu(av.z + ad.z) - M2) * i2);
        u64 pk = (u64)q0 | ((u64)q1 << 21) | ((u64)q2 << 42);
        atomicAdd(&wp[s], pk);
    }
}

// gsum[j] = sum_n (sum_p unpack(wpk[p*N+n], j/64)) * gh[n,j]
__global__ __launch_bounds__(192) void k_wsum(const u64* __restrict__ wpk,
                                              const __half* __restrict__ gh,
                                              float* __restrict__ gsum, int N) {
    int j = threadIdx.x;
    int sh = 21 * (j >> 6);
    int gs = gridDim.x;
    float a = 0.f;
    for (int n = blockIdx.x; n < N; n += gs) {
        float wn = 0.f;
#pragma unroll
        for (int p = 0; p < 8; p++) {
            u64 pk = wpk[(size_t)p * N + n];
            wn += (float)((u32)(pk >> sh) & 0x1FFFFFu);
        }
        a += wn * __half2float(gh[(size_t)n * 192 + j]);
    }
    atomicAdd(&gsum[j], a);
}

__global__ void k_final(const float* __restrict__ gsum, const float* __restrict__ b2,
                        float* __restrict__ out, float inv) {
    int j = threadIdx.x;
    if (j < 192) out[j] = gsum[j] * inv + b2[j];
}

// ---------- launcher ----------
extern "C" void kernel_launch(void* const* d_in, const int* in_sizes, int n_in,
                              void* d_out, int out_size, void* d_ws, size_t ws_size,
                              hipStream_t stream) {
    const float* X   = (const float*)d_in[0];
    const int*   ei  = (const int*)d_in[1];
    const float* ew  = (const float*)d_in[2];
    const float* W1  = (const float*)d_in[3];
    const float* b1  = (const float*)d_in[4];
    const float* W2  = (const float*)d_in[5];
    const float* b2  = (const float*)d_in[6];
    const float* ats = (const float*)d_in[7];
    const float* atd = (const float*)d_in[8];

    int N  = in_sizes[0] / 128;
    int E  = in_sizes[1] / 2;
    int Et = E + N;
    const int* srcI = ei;
    const int* dstI = ei + E;

    float* ws = (float*)d_ws;
    int*   wsi = (int*)d_ws;

    size_t o = 0;
    int* off_p = wsi + o;           o += (size_t)N + 1;
    int* cur_p = wsi + o;           o += (size_t)N + 1;
    o = (o + 1) & ~(size_t)1;                              // 8B align
    size_t z0 = o;
    u64* wpk   = (u64*)(wsi + o);   o += (size_t)N * 16;   // 8 XCD copies, zeroed
    int* cnt_p = wsi + o;           o += (size_t)N;        // zeroed
    float* gsum = ws + o;           o += 192;              // zeroed
    u32* amaxk = (u32*)(wsi + o);   o += 4;                // zeroed (fkey -inf)
    size_t z1 = o;
    int* part_p = wsi + o;          o += 256;
    float* dis  = ws + o;           o += (size_t)N;
    o = (o + 3) & ~(size_t)3;                              // 16B align
    float* asrc4 = ws + o;          o += (size_t)N * 4;
    float* adst4 = ws + o;          o += (size_t)N * 4;
    float* x     = ws + o;          o += (size_t)N * 64;
    __half* xwh  = (__half*)(ws + o); o += (size_t)N * 32;
    __half* gh   = (__half*)(ws + o); o += (size_t)N * 96;
    u32* epk = (u32*)(ws + o);

    hipMemsetAsync(wsi + z0, 0, (z1 - z0) * sizeof(int), stream);

    int nb = (N + 1023) / 1024;

    k_hist <<<2048, 256, 0, stream>>>(dstI, cnt_p, E, N);
    k_scan1<<<nb, 256, 0, stream>>>(cnt_p, off_p, part_p, N);
    k_scan2<<<1, 256, 0, stream>>>(part_p, nb);
    k_scan3<<<nb, 256, 0, stream>>>(off_p, cur_p, part_p, N, Et);
    k_fill <<<2048, 256, 0, stream>>>(srcI, dstI, ew, cur_p, epk, E, Et, N);
    k_degdis<<<(N + 255) / 256, 256, 0, stream>>>(off_p, epk, dis, N);
    k_gemm1<<<N / 32, 256, 0, stream>>>(X, W1, dis, xwh, N);
    k_gcn_agg<<<2048, 256, 0, stream>>>(off_p, epk, dis, xwh, x, N);
    k_gemm2<<<N / 32, 256, 0, stream>>>(x, W2, b1, ats, atd, gh, asrc4, adst4, amaxk, N);
    k_gatsm<<<(4 * N + 255) / 256, 256, 0, stream>>>(off_p, epk, asrc4, adst4, amaxk, wpk, N);
    k_wsum<<<512, 192, 0, stream>>>(wpk, gh, gsum, N);
    k_final<<<1, 192, 0, stream>>>(gsum, b2, (float*)d_out, 1.0f / (8192.0f * (float)N));
}

// Round 10
// 611.403 us; speedup vs baseline: 1.0238x; 1.0238x over previous
//
#include <hip/hip_runtime.h>
#include <hip/hip_fp16.h>
#include <math.h>

typedef unsigned long long u64;
typedef unsigned int u32;

__device__ __forceinline__ float lrelu(float v) { return v > 0.f ? v : 0.2f * v; }
__device__ __forceinline__ u32 fkey(float x) {
    u32 b = __float_as_uint(x);
    return (b & 0x80000000u) ? ~b : (b | 0x80000000u);
}
__device__ __forceinline__ float finv(u32 k) {
    return __uint_as_float((k & 0x80000000u) ? (k & 0x7fffffffu) : ~k);
}

union H2U { __half2 h; u32 u; };

// ---------- CSR build (dst-CSR, packed u32: w15<<17 | src17) ----------
// k_hist / k_fill / k_gatsm are XCD-partitioned: blockIdx%8 -> XCD (round-robin
// dispatch); exclusive dst-ranges (hist/fill) or private wpk copies (gatsm) keep
// scattered-RMW lines resident in ONE XCD L2 -> written back once.

__global__ __launch_bounds__(256) void k_hist(const int* __restrict__ dst,
                                              int* __restrict__ cnt, int E, int N) {
    int p = blockIdx.x & 7;
    int lo = (int)((long long)p * N / 8);
    int hi = (int)((long long)(p + 1) * N / 8);
    int bi = blockIdx.x >> 3;
    int nb = gridDim.x >> 3;
    for (int e = bi * 256 + threadIdx.x; e < E; e += nb * 256) {
        int d = dst[e];
        if (d >= lo && d < hi) atomicAdd(&cnt[d], 1);
    }
}

__global__ __launch_bounds__(256) void k_scan1(const int* __restrict__ cnt,
                                               int* __restrict__ off,
                                               int* __restrict__ partials, int N) {
    __shared__ int sh[256];
    int tid = threadIdx.x;
    int base = blockIdx.x * 1024 + tid * 4;
    int v[4]; int tsum = 0;
#pragma unroll
    for (int i = 0; i < 4; i++) {
        int n = base + i;
        int c = (n < N) ? cnt[n] + 1 : 0;
        v[i] = tsum; tsum += c;
    }
    sh[tid] = tsum; __syncthreads();
    int mine = tsum;
    for (int o = 1; o < 256; o <<= 1) {
        int t = (tid >= o) ? sh[tid - o] : 0;
        __syncthreads();
        sh[tid] += t;
        __syncthreads();
    }
    int excl = sh[tid] - mine;
#pragma unroll
    for (int i = 0; i < 4; i++) {
        int n = base + i;
        if (n < N) off[n] = excl + v[i];
    }
    if (tid == 255) partials[blockIdx.x] = sh[255];
}

__global__ void k_scan2(int* __restrict__ partials, int nb) {
    __shared__ int sh[256];
    int tid = threadIdx.x;
    int v = (tid < nb) ? partials[tid] : 0;
    sh[tid] = v; __syncthreads();
    for (int o = 1; o < 256; o <<= 1) {
        int t = (tid >= o) ? sh[tid - o] : 0;
        __syncthreads();
        sh[tid] += t;
        __syncthreads();
    }
    if (tid < nb) partials[tid] = sh[tid] - v;
}

__global__ void k_scan3(int* __restrict__ off, int* __restrict__ cursor,
                        const int* __restrict__ partials, int N, int Et) {
    int base = blockIdx.x * 1024 + threadIdx.x * 4;
    int add = partials[blockIdx.x];
#pragma unroll
    for (int i = 0; i < 4; i++) {
        int n = base + i;
        if (n < N) { int o = off[n] + add; off[n] = o; cursor[n] = o; }
    }
    if (blockIdx.x == 0 && threadIdx.x == 0) { off[N] = Et; cursor[N] = Et; }
}

__global__ __launch_bounds__(256) void k_fill(const int* __restrict__ src,
                                              const int* __restrict__ dst,
                                              const float* __restrict__ ew,
                                              int* __restrict__ cursor,
                                              u32* __restrict__ epk,
                                              int E, int Et, int N) {
    int p = blockIdx.x & 7;
    int lo = (int)((long long)p * N / 8);
    int hi = (int)((long long)(p + 1) * N / 8);
    int bi = blockIdx.x >> 3;
    int nb = gridDim.x >> 3;
    for (int e = bi * 256 + threadIdx.x; e < Et; e += nb * 256) {
        int d = (e < E) ? dst[e] : e - E;
        if (d < lo || d >= hi) continue;
        int s; u32 q;
        if (e < E) {
            s = src[e];
            q = min(__float2uint_rn(ew[e] * 32767.f), 32767u);
        } else { s = d; q = 32767u; }
        int pos = atomicAdd(&cursor[d], 1);
        epk[pos] = (q << 17) | (u32)s;
    }
}

__global__ void k_degdis(const int* __restrict__ off, const u32* __restrict__ epk,
                         float* __restrict__ dis, int N) {
    int n = blockIdx.x * 256 + threadIdx.x;
    if (n >= N) return;
    int b = off[n], e2 = off[n + 1];
    float s = 0.f;
    for (int i = b; i < e2; i++) s += (float)(epk[i] >> 17);
    dis[n] = rsqrtf(s * (1.f / 32767.f));
}

// ---------- dense kernels ----------

// xwh[n] = f16( dis[n] * (X @ W1)[n] )
__global__ __launch_bounds__(256) void k_gemm1(const float* __restrict__ X,
                                               const float* __restrict__ W1,
                                               const float* __restrict__ dis,
                                               __half* __restrict__ xwh, int N) {
    __shared__ __align__(16) float Ws[128 * 64];
    __shared__ __align__(16) float Xs[32][129];
    int tid = threadIdx.x;
    int m0 = blockIdx.x * 32;
    const float4* W4 = (const float4*)W1;
    float4* Ws4 = (float4*)Ws;
#pragma unroll
    for (int i = 0; i < 8; i++) Ws4[tid + i * 256] = W4[tid + i * 256];
#pragma unroll
    for (int i = 0; i < 4; i++) {
        int idx = tid + i * 256;
        int r = idx >> 5;
        int c = idx & 31;
        float4 v = ((const float4*)(X + (size_t)(m0 + r) * 128))[c];
        Xs[r][c * 4 + 0] = v.x; Xs[r][c * 4 + 1] = v.y;
        Xs[r][c * 4 + 2] = v.z; Xs[r][c * 4 + 3] = v.w;
    }
    __syncthreads();
    int r = tid & 31;
    int c0 = (tid >> 5) * 8;
    float acc[8] = {0, 0, 0, 0, 0, 0, 0, 0};
#pragma unroll 4
    for (int k = 0; k < 128; k++) {
        float xv = Xs[r][k];
        const float4* wr = (const float4*)&Ws[k * 64 + c0];
        float4 w0 = wr[0], w1 = wr[1];
        acc[0] += xv * w0.x; acc[1] += xv * w0.y; acc[2] += xv * w0.z; acc[3] += xv * w0.w;
        acc[4] += xv * w1.x; acc[5] += xv * w1.y; acc[6] += xv * w1.z; acc[7] += xv * w1.w;
    }
    float dn = dis[m0 + r];
    H2U p0, p1, p2, p3;
    p0.h = __floats2half2_rn(acc[0] * dn, acc[1] * dn);
    p1.h = __floats2half2_rn(acc[2] * dn, acc[3] * dn);
    p2.h = __floats2half2_rn(acc[4] * dn, acc[5] * dn);
    p3.h = __floats2half2_rn(acc[6] * dn, acc[7] * dn);
    ((uint4*)(xwh + (size_t)(m0 + r) * 64))[c0 >> 3] = make_uint4(p0.u, p1.u, p2.u, p3.u);
}

// x[n] = dis[n] * sum_{e in CSR(n)} w_e * xwh[src]   (8 edge-slots x 8 lanes)
__global__ __launch_bounds__(256) void k_gcn_agg(const int* __restrict__ off,
                                                 const u32* __restrict__ epk,
                                                 const float* __restrict__ dis,
                                                 const __half* __restrict__ xwh,
                                                 float* __restrict__ x, int N) {
    int lane = threadIdx.x & 63;
    int wv = threadIdx.x >> 6;
    int slot = lane >> 3;
    int f8 = lane & 7;
    int gw = blockIdx.x * 4 + wv;
    int stride = gridDim.x * 4;
    for (int n = gw; n < N; n += stride) {
        int b = off[n], en = off[n + 1];
        float acc[8] = {0, 0, 0, 0, 0, 0, 0, 0};
        for (int c = b; c < en; c += 64) {
            int idx = c + lane;
            int s = 0; float nw = 0.f;
            if (idx < en) {
                u32 pk = epk[idx];
                s = (int)(pk & 0x1FFFFu);
                nw = (float)(pk >> 17) * (1.f / 32767.f);
            }
            int cc = min(64, en - c);
            for (int r = 0; r * 8 < cc; r++) {
                int eo = r * 8 + slot;
                int ss = __shfl(s, eo);
                float nn = __shfl(nw, eo);
                if (eo < cc) {
                    uint4 raw = ((const uint4*)(xwh + (size_t)ss * 64))[f8];
                    __half2* hp = (__half2*)&raw;
                    float2 q0 = __half22float2(hp[0]);
                    float2 q1 = __half22float2(hp[1]);
                    float2 q2 = __half22float2(hp[2]);
                    float2 q3 = __half22float2(hp[3]);
                    acc[0] += nn * q0.x; acc[1] += nn * q0.y;
                    acc[2] += nn * q1.x; acc[3] += nn * q1.y;
                    acc[4] += nn * q2.x; acc[5] += nn * q2.y;
                    acc[6] += nn * q3.x; acc[7] += nn * q3.y;
                }
            }
        }
#pragma unroll
        for (int j = 0; j < 8; j++) {
            acc[j] += __shfl_xor(acc[j], 8);
            acc[j] += __shfl_xor(acc[j], 16);
            acc[j] += __shfl_xor(acc[j], 32);
        }
        if (lane < 8) {
            float dn = dis[n];
            ((float4*)(x + (size_t)n * 64))[f8 * 2 + 0] =
                make_float4(acc[0] * dn, acc[1] * dn, acc[2] * dn, acc[3] * dn);
            ((float4*)(x + (size_t)n * 64))[f8 * 2 + 1] =
                make_float4(acc[4] * dn, acc[5] * dn, acc[6] * dn, acc[7] * dn);
        }
    }
}

// gh = f16( relu(x + b1) @ W2 ); fused epilogue: asrc4/adst4 dots + global amax
__global__ __launch_bounds__(256) void k_gemm2(const float* __restrict__ x,
                                               const float* __restrict__ W2,
                                               const float* __restrict__ b1,
                                               const float* __restrict__ att_src,
                                               const float* __restrict__ att_dst,
                                               __half* __restrict__ gh,
                                               float* __restrict__ asrc4,
                                               float* __restrict__ adst4,
                                               u32* __restrict__ amaxk, int N) {
    __shared__ __align__(16) float Ws[64 * 192];
    __shared__ __align__(16) float Xs[32][65];
    __shared__ float b1s[64];
    __shared__ float as_s[192], ad_s[192];
    int tid = threadIdx.x;
    int m0 = blockIdx.x * 32;
    if (tid < 64) b1s[tid] = b1[tid];
    if (tid < 192) { as_s[tid] = att_src[tid]; ad_s[tid] = att_dst[tid]; }
    __syncthreads();
    const float4* W4 = (const float4*)W2;
    float4* Ws4 = (float4*)Ws;
#pragma unroll
    for (int i = 0; i < 12; i++) Ws4[tid + i * 256] = W4[tid + i * 256];
#pragma unroll
    for (int i = 0; i < 2; i++) {
        int idx = tid + i * 256;
        int r = idx >> 4;
        int c4 = idx & 15;
        float4 v = ((const float4*)(x + (size_t)(m0 + r) * 64))[c4];
        v.x = fmaxf(v.x + b1s[c4 * 4 + 0], 0.f);
        v.y = fmaxf(v.y + b1s[c4 * 4 + 1], 0.f);
        v.z = fmaxf(v.z + b1s[c4 * 4 + 2], 0.f);
        v.w = fmaxf(v.w + b1s[c4 * 4 + 3], 0.f);
        Xs[r][c4 * 4 + 0] = v.x; Xs[r][c4 * 4 + 1] = v.y;
        Xs[r][c4 * 4 + 2] = v.z; Xs[r][c4 * 4 + 3] = v.w;
    }
    __syncthreads();
    int r = tid & 31;
    int c0 = (tid >> 5) * 24;
    float acc[24];
#pragma unroll
    for (int j = 0; j < 24; j++) acc[j] = 0.f;
#pragma unroll 4
    for (int k = 0; k < 64; k++) {
        float xv = Xs[r][k];
        const float4* wr = (const float4*)&Ws[k * 192 + c0];
#pragma unroll
        for (int q = 0; q < 6; q++) {
            float4 wv = wr[q];
            acc[q * 4 + 0] += xv * wv.x;
            acc[q * 4 + 1] += xv * wv.y;
            acc[q * 4 + 2] += xv * wv.z;
            acc[q * 4 + 3] += xv * wv.w;
        }
    }
    __half* outp = gh + (size_t)(m0 + r) * 192 + c0;
#pragma unroll
    for (int t = 0; t < 3; t++) {
        H2U p0, p1, p2, p3;
        p0.h = __floats2half2_rn(acc[t * 8 + 0], acc[t * 8 + 1]);
        p1.h = __floats2half2_rn(acc[t * 8 + 2], acc[t * 8 + 3]);
        p2.h = __floats2half2_rn(acc[t * 8 + 4], acc[t * 8 + 5]);
        p3.h = __floats2half2_rn(acc[t * 8 + 6], acc[t * 8 + 7]);
        ((uint4*)outp)[t] = make_uint4(p0.u, p1.u, p2.u, p3.u);
    }

    // ---- fused attention-dot epilogue (reuses Xs as scratch) ----
    float sa0 = 0.f, sa1 = 0.f, sb0 = 0.f, sb1 = 0.f;
    int h0 = c0 >> 6;
    int split = 64 - (c0 & 63); if (split > 24) split = 24;
#pragma unroll
    for (int j = 0; j < 24; j++) {
        float va = acc[j] * as_s[c0 + j];
        float vb = acc[j] * ad_s[c0 + j];
        if (j < split) { sa0 += va; sb0 += vb; }
        else           { sa1 += va; sb1 += vb; }
    }
    __syncthreads();                 // everyone done reading Xs
    float* S = &Xs[0][0];
    for (int i = tid; i < 1536; i += 256) S[i] = 0.f;
    __syncthreads();
    int ct = tid >> 5;
    int slot = (r * 8 + ct) * 3;
    S[slot + h0] = sa0;
    S[768 + slot + h0] = sb0;
    if (split < 24) { S[slot + h0 + 1] = sa1; S[768 + slot + h0 + 1] = sb1; }
    __syncthreads();
    if (tid < 96) {
        int rr = tid / 3, h = tid - 3 * rr;
        float sA = 0.f, sB = 0.f;
#pragma unroll
        for (int c = 0; c < 8; c++) {
            sA += S[(rr * 8 + c) * 3 + h];
            sB += S[768 + (rr * 8 + c) * 3 + h];
        }
        asrc4[(size_t)(m0 + rr) * 4 + h] = sA;
        adst4[(size_t)(m0 + rr) * 4 + h] = sB;
        S[1536 + tid] = sA;
    }
    __syncthreads();
    if (tid < 3) {
        float m = -1e30f;
        for (int rr = 0; rr < 32; rr++) m = fmaxf(m, S[1536 + rr * 3 + tid]);
        atomicMax(&amaxk[tid], fkey(m));
    }
}

// 4 threads per dst node: 2 sweeps (denom with safe bound M, then attn-scatter).
// attn packed: 3 heads x 21-bit fixed point (scale 8192), scattered with one u64
// atomic into the block's XCD-private wpk copy (blockIdx%8) -> no cross-XCD churn.
__global__ __launch_bounds__(256) void k_gatsm(const int* __restrict__ off,
                                               const u32* __restrict__ epk,
                                               const float* __restrict__ asrc4,
                                               const float* __restrict__ adst4,
                                               const u32* __restrict__ amaxk,
                                               u64* __restrict__ wpk, int N) {
    int gid = blockIdx.x * 256 + threadIdx.x;
    int n = gid >> 2;
    int sub = gid & 3;
    if (n >= N) return;
    u64* wp = wpk + (size_t)(blockIdx.x & 7) * N;   // XCD-private copy
    int b = off[n], en = off[n + 1];
    float4 ad = ((const float4*)adst4)[n];
    float M0 = lrelu(finv(amaxk[0]) + ad.x);   // >= per-node max (lrelu monotone)
    float M1 = lrelu(finv(amaxk[1]) + ad.y);
    float M2 = lrelu(finv(amaxk[2]) + ad.z);
    float s0 = 0.f, s1 = 0.f, s2 = 0.f;
    for (int i = b + sub; i < en; i += 4) {
        int s = (int)(epk[i] & 0x1FFFFu);
        float4 av = ((const float4*)asrc4)[s];
        s0 += __expf(lrelu(av.x + ad.x) - M0);
        s1 += __expf(lrelu(av.y + ad.y) - M1);
        s2 += __expf(lrelu(av.z + ad.z) - M2);
    }
    // combine partial denoms across the 4-thread group (lane-quad)
    s0 += __shfl_xor(s0, 1); s0 += __shfl_xor(s0, 2);
    s1 += __shfl_xor(s1, 1); s1 += __shfl_xor(s1, 2);
    s2 += __shfl_xor(s2, 1); s2 += __shfl_xor(s2, 2);
    float i0 = 8192.f / (s0 + 1e-16f);
    float i1 = 8192.f / (s1 + 1e-16f);
    float i2 = 8192.f / (s2 + 1e-16f);
    for (int i = b + sub; i < en; i += 4) {
        int s = (int)(epk[i] & 0x1FFFFu);
        float4 av = ((const float4*)asrc4)[s];
        u32 q0 = __float2uint_rn(__expf(lrelu(av.x + ad.x) - M0) * i0);
        u32 q1 = __float2uint_rn(__expf(lrelu(av.y + ad.y) - M1) * i1);
        u32 q2 = __float2uint_rn(__expf(lrelu(av.z + ad.z) - M2) * i2);
        u64 pk = (u64)q0 | ((u64)q1 << 21) | ((u64)q2 << 42);
        atomicAdd(&wp[s], pk);
    }
}

// gsum[j] = sum_n (sum_p unpack(wpk[p*N+n], j/64)) * gh[n,j]
// contiguous chunk per block (wpk line reuse) + 384 threads (2 nodes/iter)
__global__ __launch_bounds__(384) void k_wsum(const u64* __restrict__ wpk,
                                              const __half* __restrict__ gh,
                                              float* __restrict__ gsum, int N) {
    int j = threadIdx.x % 192;
    int sub = threadIdx.x / 192;     // 0..1
    int sh = 21 * (j >> 6);
    int chunk = (N + gridDim.x - 1) / gridDim.x;
    int n0 = blockIdx.x * chunk;
    int n1 = min(n0 + chunk, N);
    float a = 0.f;
    for (int n = n0 + sub; n < n1; n += 2) {
        float wn = 0.f;
#pragma unroll
        for (int p = 0; p < 8; p++) {
            u64 pk = wpk[(size_t)p * N + n];
            wn += (float)((u32)(pk >> sh) & 0x1FFFFFu);
        }
        a += wn * __half2float(gh[(size_t)n * 192 + j]);
    }
    atomicAdd(&gsum[j], a);
}

__global__ void k_final(const float* __restrict__ gsum, const float* __restrict__ b2,
                        float* __restrict__ out, float inv) {
    int j = threadIdx.x;
    if (j < 192) out[j] = gsum[j] * inv + b2[j];
}

// ---------- launcher ----------
extern "C" void kernel_launch(void* const* d_in, const int* in_sizes, int n_in,
                              void* d_out, int out_size, void* d_ws, size_t ws_size,
                              hipStream_t stream) {
    const float* X   = (const float*)d_in[0];
    const int*   ei  = (const int*)d_in[1];
    const float* ew  = (const float*)d_in[2];
    const float* W1  = (const float*)d_in[3];
    const float* b1  = (const float*)d_in[4];
    const float* W2  = (const float*)d_in[5];
    const float* b2  = (const float*)d_in[6];
    const float* ats = (const float*)d_in[7];
    const float* atd = (const float*)d_in[8];

    int N  = in_sizes[0] / 128;
    int E  = in_sizes[1] / 2;
    int Et = E + N;
    const int* srcI = ei;
    const int* dstI = ei + E;

    float* ws = (float*)d_ws;
    int*   wsi = (int*)d_ws;

    size_t o = 0;
    int* off_p = wsi + o;           o += (size_t)N + 1;
    int* cur_p = wsi + o;           o += (size_t)N + 1;
    o = (o + 1) & ~(size_t)1;                              // 8B align
    size_t z0 = o;
    u64* wpk   = (u64*)(wsi + o);   o += (size_t)N * 16;   // 8 XCD copies, zeroed
    int* cnt_p = wsi + o;           o += (size_t)N;        // zeroed
    float* gsum = ws + o;           o += 192;              // zeroed
    u32* amaxk = (u32*)(wsi + o);   o += 4;                // zeroed (fkey -inf)
    size_t z1 = o;
    int* part_p = wsi + o;          o += 256;
    float* dis  = ws + o;           o += (size_t)N;
    o = (o + 3) & ~(size_t)3;                              // 16B align
    float* asrc4 = ws + o;          o += (size_t)N * 4;
    float* adst4 = ws + o;          o += (size_t)N * 4;
    float* x     = ws + o;          o += (size_t)N * 64;
    __half* xwh  = (__half*)(ws + o); o += (size_t)N * 32;
    __half* gh   = (__half*)(ws + o); o += (size_t)N * 96;
    u32* epk = (u32*)(ws + o);

    hipMemsetAsync(wsi + z0, 0, (z1 - z0) * sizeof(int), stream);

    int nb = (N + 1023) / 1024;

    k_hist <<<2048, 256, 0, stream>>>(dstI, cnt_p, E, N);
    k_scan1<<<nb, 256, 0, stream>>>(cnt_p, off_p, part_p, N);
    k_scan2<<<1, 256, 0, stream>>>(part_p, nb);
    k_scan3<<<nb, 256, 0, stream>>>(off_p, cur_p, part_p, N, Et);
    k_fill <<<2048, 256, 0, stream>>>(srcI, dstI, ew, cur_p, epk, E, Et, N);
    k_degdis<<<(N + 255) / 256, 256, 0, stream>>>(off_p, epk, dis, N);
    k_gemm1<<<N / 32, 256, 0, stream>>>(X, W1, dis, xwh, N);
    k_gcn_agg<<<2048, 256, 0, stream>>>(off_p, epk, dis, xwh, x, N);
    k_gemm2<<<N / 32, 256, 0, stream>>>(x, W2, b1, ats, atd, gh, asrc4, adst4, amaxk, N);
    k_gatsm<<<(4 * N + 255) / 256, 256, 0, stream>>>(off_p, epk, asrc4, adst4, amaxk, wpk, N);
    k_wsum<<<1024, 384, 0, stream>>>(wpk, gh, gsum, N);
    k_final<<<1, 192, 0, stream>>>(gsum, b2, (float*)d_out, 1.0f / (8192.0f * (float)N));
}

// Round 11
// 547.704 us; speedup vs baseline: 1.1428x; 1.1163x over previous
//
#include <hip/hip_runtime.h>
#include <hip/hip_fp16.h>
#include <math.h>

typedef unsigned long long u64;
typedef unsigned int u32;

__device__ __forceinline__ float lrelu(float v) { return v > 0.f ? v : 0.2f * v; }
__device__ __forceinline__ u32 fkey(float x) {
    u32 b = __float_as_uint(x);
    return (b & 0x80000000u) ? ~b : (b | 0x80000000u);
}
__device__ __forceinline__ float finv(u32 k) {
    return __uint_as_float((k & 0x80000000u) ? (k & 0x7fffffffu) : ~k);
}

union H2U { __half2 h; u32 u; };

// ---------- CSR build (dst-CSR, packed u32: w15<<17 | src17) ----------
// k_hist / k_fill / k_gatsm are XCD-partitioned: blockIdx%8 -> XCD (round-robin
// dispatch); exclusive dst-ranges (hist/fill) or private wpk copies (gatsm) keep
// scattered-RMW lines resident in ONE XCD L2 -> written back once.

__global__ __launch_bounds__(256) void k_hist(const int* __restrict__ dst,
                                              int* __restrict__ cnt, int E, int N) {
    int p = blockIdx.x & 7;
    int lo = (int)((long long)p * N / 8);
    int hi = (int)((long long)(p + 1) * N / 8);
    int bi = blockIdx.x >> 3;
    int nb = gridDim.x >> 3;
    for (int e = bi * 256 + threadIdx.x; e < E; e += nb * 256) {
        int d = dst[e];
        if (d >= lo && d < hi) atomicAdd(&cnt[d], 1);
    }
}

__global__ __launch_bounds__(256) void k_scan1(const int* __restrict__ cnt,
                                               int* __restrict__ off,
                                               int* __restrict__ partials, int N) {
    __shared__ int sh[256];
    int tid = threadIdx.x;
    int base = blockIdx.x * 1024 + tid * 4;
    int v[4]; int tsum = 0;
#pragma unroll
    for (int i = 0; i < 4; i++) {
        int n = base + i;
        int c = (n < N) ? cnt[n] + 1 : 0;
        v[i] = tsum; tsum += c;
    }
    sh[tid] = tsum; __syncthreads();
    int mine = tsum;
    for (int o = 1; o < 256; o <<= 1) {
        int t = (tid >= o) ? sh[tid - o] : 0;
        __syncthreads();
        sh[tid] += t;
        __syncthreads();
    }
    int excl = sh[tid] - mine;
#pragma unroll
    for (int i = 0; i < 4; i++) {
        int n = base + i;
        if (n < N) off[n] = excl + v[i];
    }
    if (tid == 255) partials[blockIdx.x] = sh[255];
}

__global__ void k_scan2(int* __restrict__ partials, int nb) {
    __shared__ int sh[256];
    int tid = threadIdx.x;
    int v = (tid < nb) ? partials[tid] : 0;
    sh[tid] = v; __syncthreads();
    for (int o = 1; o < 256; o <<= 1) {
        int t = (tid >= o) ? sh[tid - o] : 0;
        __syncthreads();
        sh[tid] += t;
        __syncthreads();
    }
    if (tid < nb) partials[tid] = sh[tid] - v;
}

__global__ void k_scan3(int* __restrict__ off, int* __restrict__ cursor,
                        const int* __restrict__ partials, int N, int Et) {
    int base = blockIdx.x * 1024 + threadIdx.x * 4;
    int add = partials[blockIdx.x];
#pragma unroll
    for (int i = 0; i < 4; i++) {
        int n = base + i;
        if (n < N) { int o = off[n] + add; off[n] = o; cursor[n] = o; }
    }
    if (blockIdx.x == 0 && threadIdx.x == 0) { off[N] = Et; cursor[N] = Et; }
}

__global__ __launch_bounds__(256) void k_fill(const int* __restrict__ src,
                                              const int* __restrict__ dst,
                                              const float* __restrict__ ew,
                                              int* __restrict__ cursor,
                                              u32* __restrict__ epk,
                                              int E, int Et, int N) {
    int p = blockIdx.x & 7;
    int lo = (int)((long long)p * N / 8);
    int hi = (int)((long long)(p + 1) * N / 8);
    int bi = blockIdx.x >> 3;
    int nb = gridDim.x >> 3;
    for (int e = bi * 256 + threadIdx.x; e < Et; e += nb * 256) {
        int d = (e < E) ? dst[e] : e - E;
        if (d < lo || d >= hi) continue;
        int s; u32 q;
        if (e < E) {
            s = src[e];
            q = min(__float2uint_rn(ew[e] * 32767.f), 32767u);
        } else { s = d; q = 32767u; }
        int pos = atomicAdd(&cursor[d], 1);
        epk[pos] = (q << 17) | (u32)s;
    }
}

__global__ void k_degdis(const int* __restrict__ off, const u32* __restrict__ epk,
                         float* __restrict__ dis, int N) {
    int n = blockIdx.x * 256 + threadIdx.x;
    if (n >= N) return;
    int b = off[n], e2 = off[n + 1];
    float s = 0.f;
    for (int i = b; i < e2; i++) s += (float)(epk[i] >> 17);
    dis[n] = rsqrtf(s * (1.f / 32767.f));
}

// ---------- dense kernels ----------

// xwh[n] = f16( dis[n] * (X @ W1)[n] )
__global__ __launch_bounds__(256) void k_gemm1(const float* __restrict__ X,
                                               const float* __restrict__ W1,
                                               const float* __restrict__ dis,
                                               __half* __restrict__ xwh, int N) {
    __shared__ __align__(16) float Ws[128 * 64];
    __shared__ __align__(16) float Xs[32][129];
    int tid = threadIdx.x;
    int m0 = blockIdx.x * 32;
    const float4* W4 = (const float4*)W1;
    float4* Ws4 = (float4*)Ws;
#pragma unroll
    for (int i = 0; i < 8; i++) Ws4[tid + i * 256] = W4[tid + i * 256];
#pragma unroll
    for (int i = 0; i < 4; i++) {
        int idx = tid + i * 256;
        int r = idx >> 5;
        int c = idx & 31;
        float4 v = ((const float4*)(X + (size_t)(m0 + r) * 128))[c];
        Xs[r][c * 4 + 0] = v.x; Xs[r][c * 4 + 1] = v.y;
        Xs[r][c * 4 + 2] = v.z; Xs[r][c * 4 + 3] = v.w;
    }
    __syncthreads();
    int r = tid & 31;
    int c0 = (tid >> 5) * 8;
    float acc[8] = {0, 0, 0, 0, 0, 0, 0, 0};
#pragma unroll 4
    for (int k = 0; k < 128; k++) {
        float xv = Xs[r][k];
        const float4* wr = (const float4*)&Ws[k * 64 + c0];
        float4 w0 = wr[0], w1 = wr[1];
        acc[0] += xv * w0.x; acc[1] += xv * w0.y; acc[2] += xv * w0.z; acc[3] += xv * w0.w;
        acc[4] += xv * w1.x; acc[5] += xv * w1.y; acc[6] += xv * w1.z; acc[7] += xv * w1.w;
    }
    float dn = dis[m0 + r];
    H2U p0, p1, p2, p3;
    p0.h = __floats2half2_rn(acc[0] * dn, acc[1] * dn);
    p1.h = __floats2half2_rn(acc[2] * dn, acc[3] * dn);
    p2.h = __floats2half2_rn(acc[4] * dn, acc[5] * dn);
    p3.h = __floats2half2_rn(acc[6] * dn, acc[7] * dn);
    ((uint4*)(xwh + (size_t)(m0 + r) * 64))[c0 >> 3] = make_uint4(p0.u, p1.u, p2.u, p3.u);
}

// x[n] = dis[n] * sum_{e in CSR(n)} w_e * xwh[src]   (8 edge-slots x 8 lanes)
__global__ __launch_bounds__(256) void k_gcn_agg(const int* __restrict__ off,
                                                 const u32* __restrict__ epk,
                                                 const float* __restrict__ dis,
                                                 const __half* __restrict__ xwh,
                                                 float* __restrict__ x, int N) {
    int lane = threadIdx.x & 63;
    int wv = threadIdx.x >> 6;
    int slot = lane >> 3;
    int f8 = lane & 7;
    int gw = blockIdx.x * 4 + wv;
    int stride = gridDim.x * 4;
    for (int n = gw; n < N; n += stride) {
        int b = off[n], en = off[n + 1];
        float acc[8] = {0, 0, 0, 0, 0, 0, 0, 0};
        for (int c = b; c < en; c += 64) {
            int idx = c + lane;
            int s = 0; float nw = 0.f;
            if (idx < en) {
                u32 pk = epk[idx];
                s = (int)(pk & 0x1FFFFu);
                nw = (float)(pk >> 17) * (1.f / 32767.f);
            }
            int cc = min(64, en - c);
            for (int r = 0; r * 8 < cc; r++) {
                int eo = r * 8 + slot;
                int ss = __shfl(s, eo);
                float nn = __shfl(nw, eo);
                if (eo < cc) {
                    uint4 raw = ((const uint4*)(xwh + (size_t)ss * 64))[f8];
                    __half2* hp = (__half2*)&raw;
                    float2 q0 = __half22float2(hp[0]);
                    float2 q1 = __half22float2(hp[1]);
                    float2 q2 = __half22float2(hp[2]);
                    float2 q3 = __half22float2(hp[3]);
                    acc[0] += nn * q0.x; acc[1] += nn * q0.y;
                    acc[2] += nn * q1.x; acc[3] += nn * q1.y;
                    acc[4] += nn * q2.x; acc[5] += nn * q2.y;
                    acc[6] += nn * q3.x; acc[7] += nn * q3.y;
                }
            }
        }
#pragma unroll
        for (int j = 0; j < 8; j++) {
            acc[j] += __shfl_xor(acc[j], 8);
            acc[j] += __shfl_xor(acc[j], 16);
            acc[j] += __shfl_xor(acc[j], 32);
        }
        if (lane < 8) {
            float dn = dis[n];
            ((float4*)(x + (size_t)n * 64))[f8 * 2 + 0] =
                make_float4(acc[0] * dn, acc[1] * dn, acc[2] * dn, acc[3] * dn);
            ((float4*)(x + (size_t)n * 64))[f8 * 2 + 1] =
                make_float4(acc[4] * dn, acc[5] * dn, acc[6] * dn, acc[7] * dn);
        }
    }
}

// gh = f16( relu(x + b1) @ W2 ); fused epilogue: asrc4/adst4 dots + global amax
__global__ __launch_bounds__(256) void k_gemm2(const float* __restrict__ x,
                                               const float* __restrict__ W2,
                                               const float* __restrict__ b1,
                                               const float* __restrict__ att_src,
                                               const float* __restrict__ att_dst,
                                               __half* __restrict__ gh,
                                               float* __restrict__ asrc4,
                                               float* __restrict__ adst4,
                                               u32* __restrict__ amaxk, int N) {
    __shared__ __align__(16) float Ws[64 * 192];
    __shared__ __align__(16) float Xs[32][65];
    __shared__ float b1s[64];
    __shared__ float as_s[192], ad_s[192];
    int tid = threadIdx.x;
    int m0 = blockIdx.x * 32;
    if (tid < 64) b1s[tid] = b1[tid];
    if (tid < 192) { as_s[tid] = att_src[tid]; ad_s[tid] = att_dst[tid]; }
    __syncthreads();
    const float4* W4 = (const float4*)W2;
    float4* Ws4 = (float4*)Ws;
#pragma unroll
    for (int i = 0; i < 12; i++) Ws4[tid + i * 256] = W4[tid + i * 256];
#pragma unroll
    for (int i = 0; i < 2; i++) {
        int idx = tid + i * 256;
        int r = idx >> 4;
        int c4 = idx & 15;
        float4 v = ((const float4*)(x + (size_t)(m0 + r) * 64))[c4];
        v.x = fmaxf(v.x + b1s[c4 * 4 + 0], 0.f);
        v.y = fmaxf(v.y + b1s[c4 * 4 + 1], 0.f);
        v.z = fmaxf(v.z + b1s[c4 * 4 + 2], 0.f);
        v.w = fmaxf(v.w + b1s[c4 * 4 + 3], 0.f);
        Xs[r][c4 * 4 + 0] = v.x; Xs[r][c4 * 4 + 1] = v.y;
        Xs[r][c4 * 4 + 2] = v.z; Xs[r][c4 * 4 + 3] = v.w;
    }
    __syncthreads();
    int r = tid & 31;
    int c0 = (tid >> 5) * 24;
    float acc[24];
#pragma unroll
    for (int j = 0; j < 24; j++) acc[j] = 0.f;
#pragma unroll 4
    for (int k = 0; k < 64; k++) {
        float xv = Xs[r][k];
        const float4* wr = (const float4*)&Ws[k * 192 + c0];
#pragma unroll
        for (int q = 0; q < 6; q++) {
            float4 wv = wr[q];
            acc[q * 4 + 0] += xv * wv.x;
            acc[q * 4 + 1] += xv * wv.y;
            acc[q * 4 + 2] += xv * wv.z;
            acc[q * 4 + 3] += xv * wv.w;
        }
    }
    __half* outp = gh + (size_t)(m0 + r) * 192 + c0;
#pragma unroll
    for (int t = 0; t < 3; t++) {
        H2U p0, p1, p2, p3;
        p0.h = __floats2half2_rn(acc[t * 8 + 0], acc[t * 8 + 1]);
        p1.h = __floats2half2_rn(acc[t * 8 + 2], acc[t * 8 + 3]);
        p2.h = __floats2half2_rn(acc[t * 8 + 4], acc[t * 8 + 5]);
        p3.h = __floats2half2_rn(acc[t * 8 + 6], acc[t * 8 + 7]);
        ((uint4*)outp)[t] = make_uint4(p0.u, p1.u, p2.u, p3.u);
    }

    // ---- fused attention-dot epilogue (reuses Xs as scratch) ----
    float sa0 = 0.f, sa1 = 0.f, sb0 = 0.f, sb1 = 0.f;
    int h0 = c0 >> 6;
    int split = 64 - (c0 & 63); if (split > 24) split = 24;
#pragma unroll
    for (int j = 0; j < 24; j++) {
        float va = acc[j] * as_s[c0 + j];
        float vb = acc[j] * ad_s[c0 + j];
        if (j < split) { sa0 += va; sb0 += vb; }
        else           { sa1 += va; sb1 += vb; }
    }
    __syncthreads();                 // everyone done reading Xs
    float* S = &Xs[0][0];
    for (int i = tid; i < 1536; i += 256) S[i] = 0.f;
    __syncthreads();
    int ct = tid >> 5;
    int slot = (r * 8 + ct) * 3;
    S[slot + h0] = sa0;
    S[768 + slot + h0] = sb0;
    if (split < 24) { S[slot + h0 + 1] = sa1; S[768 + slot + h0 + 1] = sb1; }
    __syncthreads();
    if (tid < 96) {
        int rr = tid / 3, h = tid - 3 * rr;
        float sA = 0.f, sB = 0.f;
#pragma unroll
        for (int c = 0; c < 8; c++) {
            sA += S[(rr * 8 + c) * 3 + h];
            sB += S[768 + (rr * 8 + c) * 3 + h];
        }
        asrc4[(size_t)(m0 + rr) * 4 + h] = sA;
        adst4[(size_t)(m0 + rr) * 4 + h] = sB;
        S[1536 + tid] = sA;
    }
    __syncthreads();
    if (tid < 3) {
        float m = -1e30f;
        for (int rr = 0; rr < 32; rr++) m = fmaxf(m, S[1536 + rr * 3 + tid]);
        atomicMax(&amaxk[tid], fkey(m));
    }
}

// 4 threads per dst node: 2 sweeps (denom with safe bound M, then attn-scatter).
// attn packed: 3 heads x 21-bit fixed point (scale 8192), scattered with one u64
// atomic into the block's XCD-private wpk copy (blockIdx%8) -> no cross-XCD churn.
__global__ __launch_bounds__(256) void k_gatsm(const int* __restrict__ off,
                                               const u32* __restrict__ epk,
                                               const float* __restrict__ asrc4,
                                               const float* __restrict__ adst4,
                                               const u32* __restrict__ amaxk,
                                               u64* __restrict__ wpk, int N) {
    int gid = blockIdx.x * 256 + threadIdx.x;
    int n = gid >> 2;
    int sub = gid & 3;
    if (n >= N) return;
    u64* wp = wpk + (size_t)(blockIdx.x & 7) * N;   // XCD-private copy
    int b = off[n], en = off[n + 1];
    float4 ad = ((const float4*)adst4)[n];
    float M0 = lrelu(finv(amaxk[0]) + ad.x);   // >= per-node max (lrelu monotone)
    float M1 = lrelu(finv(amaxk[1]) + ad.y);
    float M2 = lrelu(finv(amaxk[2]) + ad.z);
    float s0 = 0.f, s1 = 0.f, s2 = 0.f;
    for (int i = b + sub; i < en; i += 4) {
        int s = (int)(epk[i] & 0x1FFFFu);
        float4 av = ((const float4*)asrc4)[s];
        s0 += __expf(lrelu(av.x + ad.x) - M0);
        s1 += __expf(lrelu(av.y + ad.y) - M1);
        s2 += __expf(lrelu(av.z + ad.z) - M2);
    }
    // combine partial denoms across the 4-thread group (lane-quad)
    s0 += __shfl_xor(s0, 1); s0 += __shfl_xor(s0, 2);
    s1 += __shfl_xor(s1, 1); s1 += __shfl_xor(s1, 2);
    s2 += __shfl_xor(s2, 1); s2 += __shfl_xor(s2, 2);
    float i0 = 8192.f / (s0 + 1e-16f);
    float i1 = 8192.f / (s1 + 1e-16f);
    float i2 = 8192.f / (s2 + 1e-16f);
    for (int i = b + sub; i < en; i += 4) {
        int s = (int)(epk[i] & 0x1FFFFu);
        float4 av = ((const float4*)asrc4)[s];
        u32 q0 = __float2uint_rn(__expf(lrelu(av.x + ad.x) - M0) * i0);
        u32 q1 = __float2uint_rn(__expf(lrelu(av.y + ad.y) - M1) * i1);
        u32 q2 = __float2uint_rn(__expf(lrelu(av.z + ad.z) - M2) * i2);
        u64 pk = (u64)q0 | ((u64)q1 << 21) | ((u64)q2 << 42);
        atomicAdd(&wp[s], pk);
    }
}

// wf4[n] = unpack( sum_p wpk[p*N+n] ) — integer field sums are carry-safe
// (field totals equal the single-copy totals < 2^21)
__global__ void k_wred(const u64* __restrict__ wpk, float4* __restrict__ wf4, int N) {
    int n = blockIdx.x * 256 + threadIdx.x;
    if (n >= N) return;
    u64 t = 0;
#pragma unroll
    for (int p = 0; p < 8; p++) t += wpk[(size_t)p * N + n];
    wf4[n] = make_float4((float)(u32)(t & 0x1FFFFFu),
                         (float)(u32)((t >> 21) & 0x1FFFFFu),
                         (float)(u32)((t >> 42) & 0x1FFFFFu), 0.f);
}

// gsum[j] = sum_n wf4[n][j/64] * gh[n,j]
// 24 threads per node (uint4 = 8 halves each), 16 nodes in flight per block
__global__ __launch_bounds__(384) void k_wsum(const float4* __restrict__ wf4,
                                              const __half* __restrict__ gh,
                                              float* __restrict__ gsum, int N) {
    __shared__ float S[16][192];
    int t = threadIdx.x;
    int g = t / 24;        // 0..15 node slot
    int c = t - g * 24;    // 0..23 feature chunk (8 halves)
    int h = c >> 3;        // head
    int chunk = (N + gridDim.x - 1) / gridDim.x;
    int n0 = blockIdx.x * chunk;
    int n1 = min(n0 + chunk, N);
    float acc[8] = {0, 0, 0, 0, 0, 0, 0, 0};
    for (int n = n0 + g; n < n1; n += 16) {
        float wn = ((const float*)&wf4[n])[h];
        uint4 raw = *(const uint4*)(gh + (size_t)n * 192 + c * 8);
        __half2* hp = (__half2*)&raw;
        float2 f0 = __half22float2(hp[0]);
        float2 f1 = __half22float2(hp[1]);
        float2 f2 = __half22float2(hp[2]);
        float2 f3 = __half22float2(hp[3]);
        acc[0] += wn * f0.x; acc[1] += wn * f0.y;
        acc[2] += wn * f1.x; acc[3] += wn * f1.y;
        acc[4] += wn * f2.x; acc[5] += wn * f2.y;
        acc[6] += wn * f3.x; acc[7] += wn * f3.y;
    }
#pragma unroll
    for (int k = 0; k < 8; k++) S[g][c * 8 + k] = acc[k];
    __syncthreads();
    if (t < 192) {
        float a = 0.f;
#pragma unroll
        for (int gg = 0; gg < 16; gg++) a += S[gg][t];
        atomicAdd(&gsum[t], a);
    }
}

__global__ void k_final(const float* __restrict__ gsum, const float* __restrict__ b2,
                        float* __restrict__ out, float inv) {
    int j = threadIdx.x;
    if (j < 192) out[j] = gsum[j] * inv + b2[j];
}

// ---------- launcher ----------
extern "C" void kernel_launch(void* const* d_in, const int* in_sizes, int n_in,
                              void* d_out, int out_size, void* d_ws, size_t ws_size,
                              hipStream_t stream) {
    const float* X   = (const float*)d_in[0];
    const int*   ei  = (const int*)d_in[1];
    const float* ew  = (const float*)d_in[2];
    const float* W1  = (const float*)d_in[3];
    const float* b1  = (const float*)d_in[4];
    const float* W2  = (const float*)d_in[5];
    const float* b2  = (const float*)d_in[6];
    const float* ats = (const float*)d_in[7];
    const float* atd = (const float*)d_in[8];

    int N  = in_sizes[0] / 128;
    int E  = in_sizes[1] / 2;
    int Et = E + N;
    const int* srcI = ei;
    const int* dstI = ei + E;

    float* ws = (float*)d_ws;
    int*   wsi = (int*)d_ws;

    size_t o = 0;
    int* off_p = wsi + o;           o += (size_t)N + 1;
    int* cur_p = wsi + o;           o += (size_t)N + 1;
    o = (o + 1) & ~(size_t)1;                              // 8B align
    size_t z0 = o;
    u64* wpk   = (u64*)(wsi + o);   o += (size_t)N * 16;   // 8 XCD copies, zeroed
    int* cnt_p = wsi + o;           o += (size_t)N;        // zeroed
    float* gsum = ws + o;           o += 192;              // zeroed
    u32* amaxk = (u32*)(wsi + o);   o += 4;                // zeroed (fkey -inf)
    size_t z1 = o;
    int* part_p = wsi + o;          o += 256;
    float* dis  = ws + o;           o += (size_t)N;
    o = (o + 3) & ~(size_t)3;                              // 16B align
    float* asrc4 = ws + o;          o += (size_t)N * 4;
    float* adst4 = ws + o;          o += (size_t)N * 4;
    float* x     = ws + o;          o += (size_t)N * 64;
    __half* xwh  = (__half*)(ws + o); o += (size_t)N * 32;
    __half* gh   = (__half*)(ws + o); o += (size_t)N * 96;
    u32* epk = (u32*)(ws + o);
    float4* wf4 = (float4*)asrc4;   // asrc4 is dead after k_gatsm; 16B-aligned

    hipMemsetAsync(wsi + z0, 0, (z1 - z0) * sizeof(int), stream);

    int nb = (N + 1023) / 1024;

    k_hist <<<2048, 256, 0, stream>>>(dstI, cnt_p, E, N);
    k_scan1<<<nb, 256, 0, stream>>>(cnt_p, off_p, part_p, N);
    k_scan2<<<1, 256, 0, stream>>>(part_p, nb);
    k_scan3<<<nb, 256, 0, stream>>>(off_p, cur_p, part_p, N, Et);
    k_fill <<<2048, 256, 0, stream>>>(srcI, dstI, ew, cur_p, epk, E, Et, N);
    k_degdis<<<(N + 255) / 256, 256, 0, stream>>>(off_p, epk, dis, N);
    k_gemm1<<<N / 32, 256, 0, stream>>>(X, W1, dis, xwh, N);
    k_gcn_agg<<<2048, 256, 0, stream>>>(off_p, epk, dis, xwh, x, N);
    k_gemm2<<<N / 32, 256, 0, stream>>>(x, W2, b1, ats, atd, gh, asrc4, adst4, amaxk, N);
    k_gatsm<<<(4 * N + 255) / 256, 256, 0, stream>>>(off_p, epk, asrc4, adst4, amaxk, wpk, N);
    k_wred<<<(N + 255) / 256, 256, 0, stream>>>(wpk, wf4, N);
    k_wsum<<<1024, 384, 0, stream>>>(wf4, gh, gsum, N);
    k_final<<<1, 192, 0, stream>>>(gsum, b2, (float*)d_out, 1.0f / (8192.0f * (float)N));
}